// Round 6
// baseline (188.455 us; speedup 1.0000x reference)
//
#include <hip/hip_runtime.h>

#define IMG 512
#define NPLANES 48            // 16*3
#define TW 64                 // output tile width
#define TH 32                 // output tile height
#define RD 5
#define KW 11
#define VC (TW + 2*RD)        // 74 columns of vertical sums
#define WPAD 76               // flat row stride (floats), 16B-aligned rows
#define NTX (IMG/TW)          // 8
#define NTY (IMG/TH)          // 16
#define TPP (NTX*NTY)         // 128
#define NBLOCKS (NPLANES*TPP) // 6144
#define NPIX (16.0f*3.0f*512.0f*512.0f)

__device__ __forceinline__ float fast_rcp(float d) {
    float r = __builtin_amdgcn_rcpf(d);
    r = r * (2.0f - d * r);   // one Newton step: ~1e-7 rel error
    return r;
}

// symmetric 11-tap Gaussian
__device__ __forceinline__ float tap11(float x0, float x1, float x2, float x3,
                                       float x4, float x5, float x6, float x7,
                                       float x8, float x9, float x10) {
    return 0.00102838f*(x0+x10) + 0.00759876f*(x1+x9) + 0.03600077f*(x2+x8)
         + 0.10936069f*(x3+x7) + 0.21300553f*(x4+x6) + 0.26601172f*x5;
}

// LDS streams: 0=conv(u), 1=conv(v), 2=conv(u^2), 3=conv(v^2); u=a+b, v=a-b
// SSIM needs only mu1, mu2, sigma1^2+sigma2^2, sigma12 -> 4 streams suffice.
__global__ __launch_bounds__(256) void ssim_kernel(
    const float* __restrict__ img1, const float* __restrict__ img2,
    float* __restrict__ out)
{
    __shared__ __align__(16) float v[4][TH][WPAD];   // 38912 B -> 4 blocks/CU
    __shared__ float wsum[4];

    const float cw[KW] = {
        0.00102838f, 0.00759876f, 0.03600077f, 0.10936069f, 0.21300553f,
        0.26601172f,
        0.21300553f, 0.10936069f, 0.03600077f, 0.00759876f, 0.00102838f
    };

    const int tid = threadIdx.x;
    const int blk = blockIdx.x;
    const int plane = blk / TPP;
    const int t     = blk % TPP;
    const int ty0 = (t / NTX) * TH;
    const int tx0 = (t % NTX) * TW;
    const float* __restrict__ p1 = img1 + (size_t)plane * IMG * IMG;
    const float* __restrict__ p2 = img2 + (size_t)plane * IMG * IMG;

    const bool interior = (tx0 != 0) && (tx0 != IMG - TW) &&
                          (ty0 != 0) && (ty0 != IMG - TH);

    // ---- pass 1: vertical 11-tap on u,v,u^2,v^2, global -> LDS ----
    // 296 tasks: (col 0..73) x (4 row-segments of 8 outputs from 18 rows)
    // Straightforward per-output tap loop: few live accumulators, so the
    // compiler pipelines all 36 global loads (R2-style, VALUBusy ~80%).
    for (int task = tid; task < VC * 4; task += 256) {
        const int col = task % VC;       // lane -> adjacent col: coalesced
        const int seg = task / VC;
        const int gx  = tx0 + col - RD;
        const int r0  = seg * 8;
        const int gy0 = ty0 + r0 - RD;

        float u[18], w_[18];             // u=a+b, w_=a-b (36 live regs)
        if (interior) {
            const float* __restrict__ pa = p1 + (size_t)gy0 * IMG + gx;
            const float* __restrict__ pb = p2 + (size_t)gy0 * IMG + gx;
            #pragma unroll
            for (int k = 0; k < 18; k++) {
                const float av = pa[k * IMG];
                const float bv = pb[k * IMG];
                u[k]  = av + bv;
                w_[k] = av - bv;
            }
        } else {
            const bool xok = (gx >= 0) && (gx < IMG);
            #pragma unroll
            for (int k = 0; k < 18; k++) {
                const int gy = gy0 + k;
                const bool ok = xok && (gy >= 0) && (gy < IMG);
                const int gi = gy * IMG + gx;
                const float av = ok ? p1[gi] : 0.f;
                const float bv = ok ? p2[gi] : 0.f;
                u[k]  = av + bv;
                w_[k] = av - bv;
            }
        }

        #pragma unroll
        for (int o = 0; o < 8; o++) {
            float s0 = 0.f, s1 = 0.f, s2 = 0.f, s3 = 0.f;
            #pragma unroll
            for (int d = 0; d < KW; d++) {
                const float cwd = cw[d];
                const float uu = u[o + d];
                const float vv = w_[o + d];
                const float wu = cwd * uu;
                const float wv = cwd * vv;
                s0 += wu;
                s1 += wv;
                s2 += wu * uu;
                s3 += wv * vv;
            }
            const int r = r0 + o;
            v[0][r][col] = s0;           // lane->col stride-1: 2-way, free
            v[1][r][col] = s1;
            v[2][r][col] = s2;
            v[3][r][col] = s3;
        }
    }
    __syncthreads();

    // ---- pass 2: horizontal 11-tap (ds_read_b128) + SSIM ----
    const float C1 = 1e-4f;
    const float C2 = 9e-4f;
    float acc = 0.f;
    #pragma unroll
    for (int it = 0; it < 2; it++) {
        const int task = tid + it * 256;     // 0..511
        const int j = task & 15;             // outputs 4j..4j+3
        const int r = task >> 4;             // row 0..31
        float res[4][4];
        #pragma unroll
        for (int arr = 0; arr < 4; arr++) {
            const float* row = &v[arr][r][0];
            const float4 q0 = *(const float4*)(row + 4 * j);
            const float4 q1 = *(const float4*)(row + 4 * j + 4);
            const float4 q2 = *(const float4*)(row + 4 * j + 8);
            const float2 q3 = *(const float2*)(row + 4 * j + 12);
            res[arr][0] = tap11(q0.x,q0.y,q0.z,q0.w,q1.x,q1.y,q1.z,q1.w,q2.x,q2.y,q2.z);
            res[arr][1] = tap11(q0.y,q0.z,q0.w,q1.x,q1.y,q1.z,q1.w,q2.x,q2.y,q2.z,q2.w);
            res[arr][2] = tap11(q0.z,q0.w,q1.x,q1.y,q1.z,q1.w,q2.x,q2.y,q2.z,q2.w,q3.x);
            res[arr][3] = tap11(q0.w,q1.x,q1.y,q1.z,q1.w,q2.x,q2.y,q2.z,q2.w,q3.x,q3.y);
        }
        #pragma unroll
        for (int o = 0; o < 4; o++) {
            const float U = res[0][o];   // mu1+mu2
            const float V = res[1][o];   // mu1-mu2
            const float P = res[2][o];   // E[(a+b)^2]
            const float Q = res[3][o];   // E[(a-b)^2]
            const float p2 = U * U;
            const float q2 = V * V;
            const float mu12_2 = (p2 - q2) * 0.5f;   // 2*mu1*mu2
            const float musq   = (p2 + q2) * 0.5f;   // mu1^2+mu2^2
            const float e_sum  = (P + Q) * 0.5f;     // E[aa]+E[bb]
            const float e_dif  = (P - Q) * 0.5f;     // 2*E[ab]
            const float sigsum = e_sum - musq;       // s1^2+s2^2
            const float sig122 = e_dif - mu12_2;     // 2*s12
            const float num = (mu12_2 + C1) * (sig122 + C2);
            const float den = (musq + C1) * (sigsum + C2);
            acc += num * fast_rcp(den);
        }
    }

    // ---- block reduction + single atomic ----
    #pragma unroll
    for (int off = 32; off > 0; off >>= 1)
        acc += __shfl_down(acc, off, 64);
    const int lane = tid & 63;
    const int wv_i = tid >> 6;
    if (lane == 0) wsum[wv_i] = acc;
    __syncthreads();
    if (tid == 0) {
        const float total = (wsum[0] + wsum[1]) + (wsum[2] + wsum[3]);
        atomicAdd(out, total * (1.0f / NPIX));
    }
}

extern "C" void kernel_launch(void* const* d_in, const int* in_sizes, int n_in,
                              void* d_out, int out_size, void* d_ws, size_t ws_size,
                              hipStream_t stream) {
    const float* img1 = (const float*)d_in[0];
    const float* img2 = (const float*)d_in[1];
    float* out = (float*)d_out;

    hipMemsetAsync(out, 0, sizeof(float), stream);
    ssim_kernel<<<NBLOCKS, 256, 0, stream>>>(img1, img2, out);
}

// Round 7
// 188.166 us; speedup vs baseline: 1.0015x; 1.0015x over previous
//
#include <hip/hip_runtime.h>

#define IMG 512
#define NPLANES 48            // 16*3
#define TW 64                 // output tile width
#define TH 32                 // output tile height
#define RD 5
#define KW 11
#define VC (TW + 2*RD)        // 74 columns of vertical sums
#define WPAD 76               // flat row stride (floats), 16B-aligned rows
#define NTX (IMG/TW)          // 8
#define NTY (IMG/TH)          // 16
#define TPP (NTX*NTY)         // 128
#define NBLOCKS (NPLANES*TPP) // 6144
#define NPIX (16.0f*3.0f*512.0f*512.0f)

__device__ __forceinline__ float fast_rcp(float d) {
    float r = __builtin_amdgcn_rcpf(d);
    r = r * (2.0f - d * r);   // one Newton step: ~1e-7 rel error
    return r;
}

// symmetric 11-tap Gaussian
__device__ __forceinline__ float tap11(float x0, float x1, float x2, float x3,
                                       float x4, float x5, float x6, float x7,
                                       float x8, float x9, float x10) {
    return 0.00102838f*(x0+x10) + 0.00759876f*(x1+x9) + 0.03600077f*(x2+x8)
         + 0.10936069f*(x3+x7) + 0.21300553f*(x4+x6) + 0.26601172f*x5;
}

// LDS streams: 0=conv(u), 1=conv(v), 2=conv(u^2), 3=conv(v^2); u=a+b, v=a-b
// SSIM needs only mu1, mu2, sigma1^2+sigma2^2, sigma12 -> 4 streams suffice.
//
// NOTE: pass 1 deliberately has NO wave-uniform interior/boundary branch.
// A flat per-element-predicated load loop is what lets the compiler keep all
// 36 loads in flight (R2: VGPR 68, VALUBusy 80%); an if/else around the load
// loop makes it batch loads (VGPR 52, VALUBusy ~50%, +30 us).
__global__ __launch_bounds__(256) void ssim_kernel(
    const float* __restrict__ img1, const float* __restrict__ img2,
    float* __restrict__ out)
{
    __shared__ __align__(16) float v[4][TH][WPAD];   // 38912 B -> 4 blocks/CU
    __shared__ float wsum[4];

    const float cw[KW] = {
        0.00102838f, 0.00759876f, 0.03600077f, 0.10936069f, 0.21300553f,
        0.26601172f,
        0.21300553f, 0.10936069f, 0.03600077f, 0.00759876f, 0.00102838f
    };

    const int tid = threadIdx.x;
    const int blk = blockIdx.x;
    const int plane = blk / TPP;
    const int t     = blk % TPP;
    const int ty0 = (t / NTX) * TH;
    const int tx0 = (t % NTX) * TW;
    const float* __restrict__ p1 = img1 + (size_t)plane * IMG * IMG;
    const float* __restrict__ p2 = img2 + (size_t)plane * IMG * IMG;

    // ---- pass 1: vertical 11-tap on u,v,u^2,v^2, global -> LDS ----
    // 296 tasks: (col 0..73) x (4 row-segments of 8 outputs from 18 rows)
    for (int task = tid; task < VC * 4; task += 256) {
        const int col = task % VC;       // lane -> adjacent col: coalesced
        const int seg = task / VC;
        const int gx  = tx0 + col - RD;
        const int r0  = seg * 8;
        const int gy0 = ty0 + r0 - RD;
        const bool xok = (gx >= 0) && (gx < IMG);

        float u[18], w_[18];             // u=a+b, w_=a-b (36 live regs)
        #pragma unroll
        for (int k = 0; k < 18; k++) {
            const int gy = gy0 + k;
            const bool ok = xok && (gy >= 0) && (gy < IMG);
            const int gi = gy * IMG + gx;
            const float av = ok ? p1[gi] : 0.f;
            const float bv = ok ? p2[gi] : 0.f;
            u[k]  = av + bv;
            w_[k] = av - bv;
        }

        #pragma unroll
        for (int o = 0; o < 8; o++) {
            float s0 = 0.f, s1 = 0.f, s2 = 0.f, s3 = 0.f;
            #pragma unroll
            for (int d = 0; d < KW; d++) {
                const float cwd = cw[d];
                const float uu = u[o + d];
                const float vv = w_[o + d];
                const float wu = cwd * uu;
                const float wv = cwd * vv;
                s0 += wu;
                s1 += wv;
                s2 += wu * uu;
                s3 += wv * vv;
            }
            const int r = r0 + o;
            v[0][r][col] = s0;           // lane->col stride-1: 2-way, free
            v[1][r][col] = s1;
            v[2][r][col] = s2;
            v[3][r][col] = s3;
        }
    }
    __syncthreads();

    // ---- pass 2: horizontal 11-tap (ds_read_b128) + SSIM ----
    const float C1 = 1e-4f;
    const float C2 = 9e-4f;
    float acc = 0.f;
    #pragma unroll
    for (int it = 0; it < 2; it++) {
        const int task = tid + it * 256;     // 0..511
        const int j = task & 15;             // outputs 4j..4j+3
        const int r = task >> 4;             // row 0..31
        float res[4][4];
        #pragma unroll
        for (int arr = 0; arr < 4; arr++) {
            const float* row = &v[arr][r][0];
            const float4 q0 = *(const float4*)(row + 4 * j);
            const float4 q1 = *(const float4*)(row + 4 * j + 4);
            const float4 q2 = *(const float4*)(row + 4 * j + 8);
            const float2 q3 = *(const float2*)(row + 4 * j + 12);
            res[arr][0] = tap11(q0.x,q0.y,q0.z,q0.w,q1.x,q1.y,q1.z,q1.w,q2.x,q2.y,q2.z);
            res[arr][1] = tap11(q0.y,q0.z,q0.w,q1.x,q1.y,q1.z,q1.w,q2.x,q2.y,q2.z,q2.w);
            res[arr][2] = tap11(q0.z,q0.w,q1.x,q1.y,q1.z,q1.w,q2.x,q2.y,q2.z,q2.w,q3.x);
            res[arr][3] = tap11(q0.w,q1.x,q1.y,q1.z,q1.w,q2.x,q2.y,q2.z,q2.w,q3.x,q3.y);
        }
        #pragma unroll
        for (int o = 0; o < 4; o++) {
            const float U = res[0][o];   // mu1+mu2
            const float V = res[1][o];   // mu1-mu2
            const float P = res[2][o];   // E[(a+b)^2]
            const float Q = res[3][o];   // E[(a-b)^2]
            const float p2 = U * U;
            const float q2 = V * V;
            const float mu12_2 = (p2 - q2) * 0.5f;   // 2*mu1*mu2
            const float musq   = (p2 + q2) * 0.5f;   // mu1^2+mu2^2
            const float e_sum  = (P + Q) * 0.5f;     // E[aa]+E[bb]
            const float e_dif  = (P - Q) * 0.5f;     // 2*E[ab]
            const float sigsum = e_sum - musq;       // s1^2+s2^2
            const float sig122 = e_dif - mu12_2;     // 2*s12
            const float num = (mu12_2 + C1) * (sig122 + C2);
            const float den = (musq + C1) * (sigsum + C2);
            acc += num * fast_rcp(den);
        }
    }

    // ---- block reduction + single atomic ----
    #pragma unroll
    for (int off = 32; off > 0; off >>= 1)
        acc += __shfl_down(acc, off, 64);
    const int lane = tid & 63;
    const int wv_i = tid >> 6;
    if (lane == 0) wsum[wv_i] = acc;
    __syncthreads();
    if (tid == 0) {
        const float total = (wsum[0] + wsum[1]) + (wsum[2] + wsum[3]);
        atomicAdd(out, total * (1.0f / NPIX));
    }
}

extern "C" void kernel_launch(void* const* d_in, const int* in_sizes, int n_in,
                              void* d_out, int out_size, void* d_ws, size_t ws_size,
                              hipStream_t stream) {
    const float* img1 = (const float*)d_in[0];
    const float* img2 = (const float*)d_in[1];
    float* out = (float*)d_out;

    hipMemsetAsync(out, 0, sizeof(float), stream);
    ssim_kernel<<<NBLOCKS, 256, 0, stream>>>(img1, img2, out);
}